// Round 6
// baseline (165.279 us; speedup 1.0000x reference)
//
#include <hip/hip_runtime.h>
#include <hip/hip_bf16.h>

typedef __bf16 bf16;
typedef __bf16 bf16x4 __attribute__((ext_vector_type(4)));
typedef __bf16 bf16x8 __attribute__((ext_vector_type(8)));
typedef float f32x4 __attribute__((ext_vector_type(4)));
typedef float f32x16 __attribute__((ext_vector_type(16)));

#define NB 8
#define NS 2048
#define ND 512

static __device__ __forceinline__ f32x4 mfma16(bf16x8 a, bf16x8 b, f32x4 c) {
  return __builtin_amdgcn_mfma_f32_16x16x32_bf16(a, b, c, 0, 0, 0);
}
static __device__ __forceinline__ f32x16 mfma32(bf16x8 a, bf16x8 b, f32x16 c) {
  return __builtin_amdgcn_mfma_f32_32x32x16_bf16(a, b, c, 0, 0, 0);
}
static __device__ __forceinline__ void async16(const bf16* g, bf16* l) {
  __builtin_amdgcn_global_load_lds((const __attribute__((address_space(1))) void*)g,
                                   (__attribute__((address_space(3))) void*)l, 16, 0, 0);
}

// raw barriers: counted vmcnt keeps prefetch DMA in flight across barriers (T3/T4)
#define BAR_VM8_LG0() do { asm volatile("s_waitcnt vmcnt(8) lgkmcnt(0)" ::: "memory"); \
  __builtin_amdgcn_s_barrier(); __builtin_amdgcn_sched_barrier(0); } while (0)
#define BAR_LG0() do { asm volatile("s_waitcnt lgkmcnt(0)" ::: "memory"); \
  __builtin_amdgcn_s_barrier(); __builtin_amdgcn_sched_barrier(0); } while (0)

// ---- kernel 0: W[k][n] (f32) -> Wt[z][n][k^((n&7)<<3)] (bf16, pre-swizzled).
// Wq additionally scaled by rsqrt(512)*log2e (folds softmax scale into Q).
__global__ void wconv_kernel(const float* __restrict__ Wq,
                             const float* __restrict__ Wk,
                             const float* __restrict__ Wv,
                             bf16* __restrict__ Wt) {
  __shared__ float buf[64][65];
  const int z = blockIdx.z;
  const float* W = (z == 0) ? Wq : (z == 1) ? Wk : Wv;
  const float scale = (z == 0) ? 0.063763537f : 1.0f;
  const int k0 = blockIdx.x * 64, n0 = blockIdx.y * 64;
  const int t = threadIdx.x;
#pragma unroll
  for (int i = 0; i < 16; ++i) {
    int idx = i * 256 + t;
    int kk = idx >> 6, nn = idx & 63;
    buf[kk][nn] = W[(size_t)(k0 + kk) * 512 + n0 + nn];
  }
  __syncthreads();
#pragma unroll
  for (int i = 0; i < 16; ++i) {
    int idx = i * 256 + t;
    int nn = idx >> 6, kk = idx & 63;
    Wt[(size_t)z * 262144 + (size_t)(n0 + nn) * 512 + k0 + (kk ^ ((nn & 7) << 3))] =
        (bf16)(buf[kk][nn] * scale);
  }
}

// ---- kernel 1: fused 3x projection C[16384,512] = A_f32 @ W, bf16 out ----
// W staged via global_load_lds (linear LDS, global pre-swizzled, XOR on read).
// z=0: Q plain; z=1: K col-swizzled per row; z=2: V^T [B][512][2048] s-swizzled.
__launch_bounds__(256)
__global__ void proj_kernel(const float* __restrict__ Xq,
                            const float* __restrict__ Xk,
                            const float* __restrict__ Xv,
                            const bf16* __restrict__ Wt,
                            bf16* __restrict__ Cq,
                            bf16* __restrict__ Ck,
                            bf16* __restrict__ Cv) {
  __shared__ bf16 As[2][128][72];
  __shared__ bf16 WsL[2][8192];    // [128 n][64 k] linear (DMA dest)
  const int z = blockIdx.z;
  const float* A = (z == 0) ? Xq : (z == 1) ? Xk : Xv;
  const bf16* Wz = Wt + (size_t)z * 262144;
  bf16* C = (z == 0) ? Cq : (z == 1) ? Ck : Cv;

  const int t = threadIdx.x;
  const int lane = t & 63;
  const int w = t >> 6;
  const int wr = w >> 1, wc = w & 1;
  const int bxr = blockIdx.x;
  const int mt = (bxr & 7) * 16 + (bxr >> 3);   // batch-pinned M-tile
  const int bm = mt * 128;
  const int bn = blockIdx.y * 128;

  f32x4 acc[4][4] = {};

  auto stageA = [&](int kc, int bufi) {
    int r0 = t >> 4, seg = t & 15;
#pragma unroll
    for (int p = 0; p < 8; ++p) {
      int r = p * 16 + r0;
      float4 v = *(const float4*)(A + (size_t)(bm + r) * 512 + kc * 64 + seg * 4);
      bf16x4 o = {(bf16)v.x, (bf16)v.y, (bf16)v.z, (bf16)v.w};
      *(bf16x4*)&As[bufi][r][seg * 4] = o;
    }
  };
  auto stageW = [&](int kc, int bufi) {
    const int n = t >> 3, seg = t & 7;   // 4 DMA of 16B: rows n, n+32, n+64, n+96
#pragma unroll
    for (int i = 0; i < 4; ++i)
      async16(Wz + (size_t)(bn + i * 32 + n) * 512 + kc * 64 + seg * 8,
              &WsL[bufi][(i * 32 + n) * 64 + seg * 8]);
  };

  stageW(0, 0);
  stageA(0, 0);
  __syncthreads();
  int buf = 0;
  for (int kc = 0; kc < 8; ++kc) {
    if (kc < 7) { stageW(kc + 1, buf ^ 1); stageA(kc + 1, buf ^ 1); }
    const int arow = lane & 15, kq = (lane >> 4) * 8;
#pragma unroll
    for (int kk = 0; kk < 2; ++kk) {
      bf16x8 af[4], bfr[4];
#pragma unroll
      for (int mi = 0; mi < 4; ++mi)
        af[mi] = *(const bf16x8*)&As[buf][wr * 64 + mi * 16 + arow][kk * 32 + kq];
#pragma unroll
      for (int ni = 0; ni < 4; ++ni) {
        int n = wc * 64 + ni * 16 + arow;
        bfr[ni] = *(const bf16x8*)&WsL[buf][n * 64 + ((kk * 32 + kq) ^ ((n & 7) << 3))];
      }
#pragma unroll
      for (int mi = 0; mi < 4; ++mi)
#pragma unroll
        for (int ni = 0; ni < 4; ++ni)
          acc[mi][ni] = mfma16(af[mi], bfr[ni], acc[mi][ni]);
    }
    __syncthreads();
    buf ^= 1;
  }

  const int row0 = (lane >> 4) * 4, col = lane & 15;
#pragma unroll
  for (int mi = 0; mi < 4; ++mi)
#pragma unroll
    for (int ni = 0; ni < 4; ++ni) {
      int cg = bn + wc * 64 + ni * 16 + col;
#pragma unroll
      for (int j = 0; j < 4; ++j) {
        int rg = bm + wr * 64 + mi * 16 + row0 + j;
        bf16 o = (bf16)acc[mi][ni][j];
        if (z == 0) {
          C[(size_t)rg * ND + cg] = o;
        } else if (z == 1) {
          C[(size_t)rg * ND + (cg ^ ((rg & 7) << 3))] = o;
        } else {
          int bb = rg >> 11, s = rg & 2047;
          int ss = (s & ~63) | ((s & 63) ^ ((cg & 7) << 3));
          C[(size_t)bb * (ND * NS) + (size_t)cg * NS + ss] = o;
        }
      }
    }
}

// ---- kernel 2: causal flash attention, split-KV capable ----
// QK: mfma32, waves (sm,sn,sk) = (q-half, kv-half, K-half), Ss partial reduce.
// Pipeline per 64-KV tile (counted vmcnt, never 0 in loop):
//  B1[vm8] QK  B2[lg0] stageK(next) + combine  B3[lg0] softmax
//  B4[vm8+lg0] PV  B5[lg0] stageV(next)
template<int NSPLIT>
__launch_bounds__(512, 2)
__global__ void attn_kernel(const bf16* __restrict__ Qg,
                            const bf16* __restrict__ Kg,
                            const bf16* __restrict__ Vtg,
                            float* __restrict__ Out,
                            bf16* __restrict__ Pn,
                            float* __restrict__ Mp,
                            float* __restrict__ Lp) {
  __shared__ bf16 Ks[64][512];
  __shared__ bf16 Vts[512][64];
  __shared__ float Ss[64][68];
  __shared__ bf16 Ps[64][72];
  __shared__ float m_lds[64], l_lds[64], r_lds[64];

  const int t = threadIdx.x;
  const int lane = t & 63;
  const int w = t >> 6;
  const int id = blockIdx.x;
  const int b = id & 7;
  const int qt = 31 - ((id >> 3) & 31);      // descending size for greedy backfill
  const int h = (NSPLIT == 2) ? (id >> 8) : 0;
  const int q0 = qt * 64;
  const int sm = w >> 2, sn = (w >> 1) & 1, sk = w & 1;
  const int l31 = lane & 31, lhi = lane >> 5;

  int t_begin, t_end;
  {
    int nt = qt + 1;
    int mid = (nt + 1) >> 1;
    if (NSPLIT == 2) { t_begin = h ? mid : 0; t_end = h ? nt : mid; }
    else { t_begin = 0; t_end = nt; }
  }
  const int pidx = (h * 8 + b) * 32 + qt;

  if (NSPLIT == 2 && t_begin >= t_end) {       // empty half (qt=0,h=1)
    if (t < 64) { Mp[pidx * 64 + t] = -1e30f; Lp[pidx * 64 + t] = 0.0f; }
    return;
  }

  const bf16* Qb = Qg + (size_t)b * NS * ND;
  const bf16* Kb = Kg + (size_t)b * NS * ND;
  const bf16* Vb = Vtg + (size_t)b * ND * NS;

  if (t < 64) { m_lds[t] = -1e30f; l_lds[t] = 0.0f; }

  // Q fragments (A of mfma32): row = q0+sm*32+l31, k = sk*256 + kc*16 + lhi*8
  bf16x8 qf[16];
  {
    const bf16* qrow = Qb + (size_t)(q0 + sm * 32 + l31) * ND + sk * 256 + lhi * 8;
#pragma unroll
    for (int kc = 0; kc < 16; ++kc) qf[kc] = *(const bf16x8*)(qrow + kc * 16);
  }
  f32x16 acc[2][2] = {};

  auto stageK = [&](int k0s) {
#pragma unroll
    for (int i = 0; i < 8; ++i)
      async16(Kb + (size_t)(k0s + w * 8 + i) * ND + lane * 8, &Ks[w * 8 + i][0]);
  };
  auto stageV = [&](int k0s) {
#pragma unroll
    for (int i = 0; i < 8; ++i)
      async16(Vb + (size_t)(w * 64 + i * 8 + (lane >> 3)) * NS + k0s + (lane & 7) * 8,
              &Vts[w * 64 + i * 8][0]);
  };

  stageK(t_begin * 64);   // 8 loads/thread (older)
  stageV(t_begin * 64);   // 8 loads/thread (newer)

  for (int it = t_begin; it < t_end; ++it) {
    const int k0 = it * 64;
    const int nx = (it + 1 < t_end ? it + 1 : it) * 64;   // clamp keeps count=8
    BAR_VM8_LG0();   // B1: K(it) landed; V(it) may still fly

    // ---- QK^T: wave (sm,sn,sk): 32q x 32kv over K=256 -> 16 mfma32 ----
    __builtin_amdgcn_s_setprio(1);
    f32x16 sacc = {};
    const int kvr = sn * 32 + l31;
    const int swz = (kvr & 7) << 3;
#pragma unroll
    for (int kc = 0; kc < 16; ++kc) {
      int col = (sk * 256 + kc * 16 + lhi * 8) ^ swz;
      bf16x8 bfrag = *(const bf16x8*)&Ks[kvr][col];
      sacc = mfma32(qf[kc], bfrag, sacc);
    }
    __builtin_amdgcn_s_setprio(0);
    if (sk) {
#pragma unroll
      for (int j = 0; j < 16; ++j) {
        int row = (j & 3) + 8 * (j >> 2) + 4 * lhi;
        Ss[sm * 32 + row][sn * 32 + l31] = sacc[j];
      }
    }
    BAR_LG0();       // B2: partials visible; all QK reads of Ks retired
    stageK(nx);      // prefetch next K (window: combine+softmax+PV)
    if (!sk) {
      const bool mask = (it == qt);
#pragma unroll
      for (int j = 0; j < 16; ++j) {
        int row = (j & 3) + 8 * (j >> 2) + 4 * lhi;
        int q = sm * 32 + row, kvc = sn * 32 + l31;
        float v = sacc[j] + Ss[q][kvc];
        if (mask && (k0 + kvc > q0 + q)) v = -1e30f;
        Ss[q][kvc] = v;
      }
    }
    BAR_LG0();       // B3: combined scores visible

    // ---- online softmax: 8 lanes per row, 64 rows ----
    {
      const int row = t >> 3, sub = t & 7;
      float4 a = *(const float4*)&Ss[row][sub * 8];
      float4 c = *(const float4*)&Ss[row][sub * 8 + 4];
      float mx = fmaxf(fmaxf(fmaxf(a.x, a.y), fmaxf(a.z, a.w)),
                       fmaxf(fmaxf(c.x, c.y), fmaxf(c.z, c.w)));
#pragma unroll
      for (int d = 1; d < 8; d <<= 1) mx = fmaxf(mx, __shfl_xor(mx, d));
      float m_old = m_lds[row];
      float m_new = fmaxf(m_old, mx);
      float p0 = exp2f(a.x - m_new), p1 = exp2f(a.y - m_new);
      float p2 = exp2f(a.z - m_new), p3 = exp2f(a.w - m_new);
      float p4 = exp2f(c.x - m_new), p5 = exp2f(c.y - m_new);
      float p6 = exp2f(c.z - m_new), p7 = exp2f(c.w - m_new);
      float sum = ((p0 + p1) + (p2 + p3)) + ((p4 + p5) + (p6 + p7));
#pragma unroll
      for (int d = 1; d < 8; d <<= 1) sum += __shfl_xor(sum, d);
      bf16x8 pv = {(bf16)p0, (bf16)p1, (bf16)p2, (bf16)p3,
                   (bf16)p4, (bf16)p5, (bf16)p6, (bf16)p7};
      *(bf16x8*)&Ps[row][sub * 8] = pv;
      if (sub == 0) {
        float rs = exp2f(m_old - m_new);
        r_lds[row] = rs;
        m_lds[row] = m_new;
        l_lds[row] = l_lds[row] * rs + sum;
      }
    }
    BAR_VM8_LG0();   // B4: V(it) landed; K(next) still flying; Ps visible

    // ---- PV: wave w owns d in [w*64, w*64+64) ----
    __builtin_amdgcn_s_setprio(1);
#pragma unroll
    for (int mi = 0; mi < 2; ++mi)
#pragma unroll
      for (int j = 0; j < 16; ++j) {
        int row = mi * 32 + (j & 3) + 8 * (j >> 2) + 4 * lhi;
        float rs = r_lds[row];
        acc[mi][0][j] *= rs;
        acc[mi][1][j] *= rs;
      }
#pragma unroll
    for (int kc = 0; kc < 4; ++kc) {
      const int kv0 = kc * 16 + lhi * 8;
      bf16x8 pa0 = *(const bf16x8*)&Ps[l31][kv0];
      bf16x8 pa1 = *(const bf16x8*)&Ps[32 + l31][kv0];
      bf16x8 vb0, vb1;
      { int d0 = w * 64 + l31;      vb0 = *(const bf16x8*)&Vts[d0][kv0 ^ ((d0 & 7) << 3)]; }
      { int d1 = w * 64 + 32 + l31; vb1 = *(const bf16x8*)&Vts[d1][kv0 ^ ((d1 & 7) << 3)]; }
      acc[0][0] = mfma32(pa0, vb0, acc[0][0]);
      acc[0][1] = mfma32(pa0, vb1, acc[0][1]);
      acc[1][0] = mfma32(pa1, vb0, acc[1][0]);
      acc[1][1] = mfma32(pa1, vb1, acc[1][1]);
    }
    __builtin_amdgcn_s_setprio(0);
    BAR_LG0();       // B5: PV reads of Vts/Ps retired
    stageV(nx);      // prefetch next V (window: QK+combine+softmax of next tile)
  }

  // ---- epilogue ----
  if (NSPLIT == 2) {
    if (t < 64) { Mp[pidx * 64 + t] = m_lds[t]; Lp[pidx * 64 + t] = l_lds[t]; }
    bf16* Ob = Pn + (size_t)pidx * 64 * ND;
#pragma unroll
    for (int mi = 0; mi < 2; ++mi)
#pragma unroll
      for (int j = 0; j < 16; ++j) {
        int row = mi * 32 + (j & 3) + 8 * (j >> 2) + 4 * lhi;
        float inv = 1.0f / l_lds[row];
#pragma unroll
        for (int ni = 0; ni < 2; ++ni)
          Ob[(size_t)row * ND + w * 64 + ni * 32 + l31] = (bf16)(acc[mi][ni][j] * inv);
      }
  } else {
    float* Ob = Out + (size_t)b * NS * ND;
#pragma unroll
    for (int mi = 0; mi < 2; ++mi)
#pragma unroll
      for (int j = 0; j < 16; ++j) {
        int row = mi * 32 + (j & 3) + 8 * (j >> 2) + 4 * lhi;
        float inv = 1.0f / l_lds[row];
#pragma unroll
        for (int ni = 0; ni < 2; ++ni)
          __builtin_nontemporal_store(acc[mi][ni][j] * inv,
              &Ob[(size_t)(q0 + row) * ND + w * 64 + ni * 32 + l31]);
      }
  }
}

// ---- kernel 3: combine two KV-half partials ----
__global__ void combine_kernel(const bf16* __restrict__ Pn,
                               const float* __restrict__ Mp,
                               const float* __restrict__ Lp,
                               float* __restrict__ Out) {
  const int total = NB * NS * ND / 4;
  for (int v = blockIdx.x * 256 + threadIdx.x; v < total; v += gridDim.x * 256) {
    int e = v * 4;
    int d = e & 511;
    int s = (e >> 9) & 2047;
    int bb = e >> 20;
    int qt = s >> 6, r = s & 63;
    int p0 = (bb * 32 + qt) * 64 + r;
    int p1 = ((8 + bb) * 32 + qt) * 64 + r;
    float m0 = Mp[p0], l0 = Lp[p0], m1 = Mp[p1], l1 = Lp[p1];
    float M = fmaxf(m0, m1);
    float w0 = l0 * exp2f(m0 - M), w1 = l1 * exp2f(m1 - M);
    float inv = 1.0f / (w0 + w1);
    bf16x4 o0 = *(const bf16x4*)(Pn + (size_t)p0 * ND + d);
    bf16x4 o1 = *(const bf16x4*)(Pn + (size_t)p1 * ND + d);
    f32x4 o;
    o[0] = (w0 * (float)o0[0] + w1 * (float)o1[0]) * inv;
    o[1] = (w0 * (float)o0[1] + w1 * (float)o1[1]) * inv;
    o[2] = (w0 * (float)o0[2] + w1 * (float)o1[2]) * inv;
    o[3] = (w0 * (float)o0[3] + w1 * (float)o1[3]) * inv;
    __builtin_nontemporal_store(o, (f32x4*)(Out + e));
  }
}

extern "C" void kernel_launch(void* const* d_in, const int* in_sizes, int n_in,
                              void* d_out, int out_size, void* d_ws, size_t ws_size,
                              hipStream_t stream) {
  const float* Xk = (const float*)d_in[0];
  const float* Xv = (const float*)d_in[1];
  const float* Xq = (const float*)d_in[2];
  const float* Wq = (const float*)d_in[3];
  const float* Wk = (const float*)d_in[4];
  const float* Wv = (const float*)d_in[5];
  float* Out = (float*)d_out;

  char* ws = (char*)d_ws;
  bf16* Qb = (bf16*)(ws);                                    // 16 MB
  bf16* Kb = (bf16*)(ws + (size_t)16 * 1024 * 1024);         // 16 MB (swizzled)
  bf16* Vt = (bf16*)(ws + (size_t)32 * 1024 * 1024);         // 16 MB (transposed+swizzled)
  bf16* Wt = (bf16*)(ws + (size_t)48 * 1024 * 1024);         // 1.5 MB (pre-swizzled)
  bf16* Pn = (bf16*)(ws + (size_t)50 * 1024 * 1024);         // 32 MB partials
  float* Mp = (float*)(ws + (size_t)82 * 1024 * 1024);       // 128 KB
  float* Lp = (float*)(ws + (size_t)82 * 1024 * 1024 + 131072);
  const bool split = ws_size >= (size_t)83 * 1024 * 1024;

  wconv_kernel<<<dim3(8, 8, 3), 256, 0, stream>>>(Wq, Wk, Wv, Wt);
  proj_kernel<<<dim3(128, 4, 3), 256, 0, stream>>>(Xq, Xk, Xv, Wt, Qb, Kb, Vt);
  if (split) {
    attn_kernel<2><<<512, 512, 0, stream>>>(Qb, Kb, Vt, Out, Pn, Mp, Lp);
    combine_kernel<<<2048, 256, 0, stream>>>(Pn, Mp, Lp, Out);
  } else {
    attn_kernel<1><<<256, 512, 0, stream>>>(Qb, Kb, Vt, Out, Pn, Mp, Lp);
  }
}